// Round 14
// baseline (145.000 us; speedup 1.0000x reference)
//
#include <hip/hip_runtime.h>

#define NPOS 16384   // D*H*W
#define KSPLIT 4
#define KEYS_PER_BLK (NPOS / KSPLIT)   // 4096
#define LOG2E 1.4426950408889634f

typedef short bf16x8 __attribute__((ext_vector_type(8)));
typedef unsigned short u16x8 __attribute__((ext_vector_type(8)));
typedef float floatx16 __attribute__((ext_vector_type(16)));
typedef float floatx2 __attribute__((ext_vector_type(2)));
typedef unsigned int uint2v __attribute__((ext_vector_type(2)));

static __device__ __forceinline__ unsigned short f2bf(float f) {
    return (unsigned short)(__builtin_bit_cast(unsigned int, f) >> 16);
}
static __device__ __forceinline__ float bf2f(unsigned short h) {
    return __builtin_bit_cast(float, (unsigned int)h << 16);
}

#if __has_builtin(__builtin_amdgcn_exp2f)
static __device__ __forceinline__ float exp2_fast(float x) {
    return __builtin_amdgcn_exp2f(x);
}
#else
static __device__ __forceinline__ float exp2_fast(float x) {
    float r;
    asm("v_exp_f32 %0, %1" : "=v"(r) : "v"(x));
    return r;
}
#endif

// sigma: swap middle two 4-key nibbles per 16 keys (involution)
static __device__ __forceinline__ int sigma(int n) {
    const int w12 = n & 12;
    return (w12 == 4 || w12 == 8) ? (n ^ 12) : n;
}

// ---------------------------------------------------------------------------
// Projection. Grid (64, 10), block 256. Thread = position n x group g.
// g==0: q[0..7] (prescaled log2e) -> qb16 [n][8] bf16.
// g==1: k[0..7] -> kb16 [n][8] bf16 (natural key order).
// g>=2: v channels (g-2)*8..+7 -> vb8 FP8 e4m3, sigma-space group-major:
//   byte index = (sigma(n)>>3)*512 + ch*8 + (sigma(n)&7)
// ---------------------------------------------------------------------------
__global__ __launch_bounds__(256) void proj_kernel(
    const float* __restrict__ x,
    const float* __restrict__ wq, const float* __restrict__ bq,
    const float* __restrict__ wk, const float* __restrict__ bk,
    const float* __restrict__ wv, const float* __restrict__ bv,
    unsigned short* __restrict__ qb16, unsigned short* __restrict__ kb16,
    unsigned char* __restrict__ vb8)
{
    const int t = threadIdx.x;
    const int n = blockIdx.x * 256 + t;
    const int g = blockIdx.y;

    const float* w;
    const float* b;
    if (g == 0)      { w = wq; b = bq; }
    else if (g == 1) { w = wk; b = bk; }
    else             { w = wv + (g - 2) * 8 * 64; b = bv + (g - 2) * 8; }

    float acc[8];
#pragma unroll
    for (int oo = 0; oo < 8; ++oo) acc[oo] = b[oo];
#pragma unroll 16
    for (int c = 0; c < 64; ++c) {
        const float xv = x[c * NPOS + n];
#pragma unroll
        for (int oo = 0; oo < 8; ++oo)
            acc[oo] = fmaf(w[oo * 64 + c], xv, acc[oo]);
    }

    if (g == 0) {
        u16x8 qp;
#pragma unroll
        for (int j = 0; j < 8; ++j) qp[j] = f2bf(acc[j] * LOG2E);
        ((uint4*)qb16)[n] = __builtin_bit_cast(uint4, qp);
    } else if (g == 1) {
        u16x8 kp;
#pragma unroll
        for (int j = 0; j < 8; ++j) kp[j] = f2bf(acc[j]);
        ((uint4*)kb16)[n] = __builtin_bit_cast(uint4, kp);
    } else {
        const int o0 = (g - 2) * 8;
        const int np = sigma(n);
        const size_t base = (size_t)(np >> 3) * 512 + (np & 7);
#pragma unroll
        for (int oo = 0; oo < 8; ++oo) {
            const unsigned int p8 =
                __builtin_amdgcn_cvt_pk_fp8_f32(acc[oo], acc[oo], 0, false);
            vb8[base + (size_t)(o0 + oo) * 8] = (unsigned char)(p8 & 0xff);
        }
    }
}

// ---------------------------------------------------------------------------
// Attention partials. Grid = 256 qblocks x 4 kq, 256 threads (4 waves).
// Wave (qhalf, khalf): 32 queries x contiguous 2048-key window. Barrier-free
// main loop, no LDS until epilogue.
//
// Scores TRANSPOSED: T = K*Q^T via mfma_32x32x16_bf16, A[m=key][k=chan]
// direct from global (no half1 zeroing: Q B-operand k>=8 rows are zero),
// B[k=chan][n=query] (half1 zero). C/D: lane(l&31)=query, row r -> key
// (r&3)+8*(r>>2)+4*half. P -> FP8 e4m3 via v_cvt_pk_fp8_f32; with V in
// sigma key order the fp8 PV A-frag f = bytes fp8(e[8f..8f+7]).
// PV: v_mfma_f32_32x32x16_fp8_fp8 (bf16 rate), V B-frags = coalesced 8B
// global loads (L2-resident).
// unroll 4: four independent tile chains in flight (R10: ILP is the lever);
// fits (256,4)'s 128-VGPR cap (fp8 freed the registers). den in 4 rotating
// accumulators to break the serial pk_add chain.
// Epilogue: khalf merge via LDS; den stored per-kq (no atomics/memset).
// ---------------------------------------------------------------------------
__global__ __launch_bounds__(256, 4) void attn_kernel(
    const uint4* __restrict__ qb4,    // [n] 8 bf16 (prescaled log2e)
    const uint4* __restrict__ kb4,    // [n] 8 bf16, natural order
    const uint2v* __restrict__ vb2,   // [key/8][64 ch] 8B fp8, sigma space
    unsigned short* __restrict__ nump,  // [4][256][2][64][32] bf16
    float* __restrict__ denp)           // [4][NPOS] fp32
{
    __shared__ __align__(16) char smem[8448];   // epilogue only

    const int t     = threadIdx.x;
    const int wave  = t >> 6;
    const int lane  = t & 63;
    const int m     = lane & 31;
    const int half  = lane >> 5;
    const int qhalf = wave >> 1;
    const int khalf = wave & 1;

    const int qblk = blockIdx.x >> 2;
    const int kq   = blockIdx.x & 3;
    const int i0   = qblk * 64;
    const int kw0  = kq * KEYS_PER_BLK + khalf * 2048;   // wave's key window

    // B operand (queries): lane m = query qhalf*32+m, regs = chans, half1 zero
    uint4 qa4 = (half == 0) ? qb4[i0 + qhalf * 32 + m] : make_uint4(0, 0, 0, 0);
    const bf16x8 bqf = __builtin_bit_cast(bf16x8, qa4);

    const uint4* kptr = kb4 + kw0 + m;   // half1 lanes mirror half0 (harmless)

    floatx16 accA = {};            // channels 0..31
    floatx16 accB = {};            // channels 32..63
    floatx2  dacc[4];              // rotating den accumulators
#pragma unroll
    for (int i = 0; i < 4; ++i) dacc[i] = (floatx2){0.f, 0.f};

#pragma unroll 4
    for (int tt = 0; tt < 64; ++tt) {
        const bf16x8 ak = __builtin_bit_cast(bf16x8, kptr[tt * 32]);
        const floatx16 s = __builtin_amdgcn_mfma_f32_32x32x16_bf16(
            ak, bqf, (floatx16){}, 0, 0, 0);

        float e[16];
#pragma unroll
        for (int r = 0; r < 16; ++r) e[r] = exp2_fast(s[r]);
#pragma unroll
        for (int p = 0; p < 8; ++p)
            dacc[p & 3] += (floatx2){e[2 * p], e[2 * p + 1]};

        const int g8t = (kw0 + tt * 32) >> 3;   // tile's 8-key group base
#pragma unroll
        for (int f = 0; f < 2; ++f) {
            unsigned int r0 =
                __builtin_amdgcn_cvt_pk_fp8_f32(e[8 * f + 0], e[8 * f + 1],
                                                0, false);
            r0 = __builtin_amdgcn_cvt_pk_fp8_f32(e[8 * f + 2], e[8 * f + 3],
                                                 (int)r0, true);
            unsigned int r1 =
                __builtin_amdgcn_cvt_pk_fp8_f32(e[8 * f + 4], e[8 * f + 5],
                                                0, false);
            r1 = __builtin_amdgcn_cvt_pk_fp8_f32(e[8 * f + 6], e[8 * f + 7],
                                                 (int)r1, true);
            const long af = __builtin_bit_cast(long, (uint2v){r0, r1});

            const int g8 = g8t + f * 2 + half;
            const long v0 = __builtin_bit_cast(long, vb2[(size_t)g8 * 64 + m]);
            const long v1 = __builtin_bit_cast(long,
                                               vb2[(size_t)g8 * 64 + 32 + m]);
            accA = __builtin_amdgcn_mfma_f32_32x32x16_fp8_fp8(af, v0, accA,
                                                              0, 0, 0);
            accB = __builtin_amdgcn_mfma_f32_32x32x16_fp8_fp8(af, v1, accB,
                                                              0, 0, 0);
        }
    }

    // per-query den for this wave (both halves end up holding it)
    const floatx2 dfold = (dacc[0] + dacc[1]) + (dacc[2] + dacc[3]);
    const float dl = dfold[0] + dfold[1];
    const float dw = dl + __shfl_xor(dl, 32);

    // khalf-pair merge via LDS
    float*          xden = (float*)smem;                    // 64 f32
    unsigned short* xacc = (unsigned short*)(smem + 256);   // [2][64][32]
    const int recl = qhalf * 64 + lane;
    if (khalf == 1) {
        if (half == 0) xden[qhalf * 32 + m] = dw;
        u16x8 a0, a1, a2, a3;
#pragma unroll
        for (int j = 0; j < 8; ++j) {
            a0[j] = f2bf(accA[j]);
            a1[j] = f2bf(accA[8 + j]);
            a2[j] = f2bf(accB[j]);
            a3[j] = f2bf(accB[8 + j]);
        }
        uint4* dst = (uint4*)(xacc + recl * 32);
        dst[0] = __builtin_bit_cast(uint4, a0);
        dst[1] = __builtin_bit_cast(uint4, a1);
        dst[2] = __builtin_bit_cast(uint4, a2);
        dst[3] = __builtin_bit_cast(uint4, a3);
    }
    __syncthreads();
    if (khalf == 0) {
        const uint4* src = (const uint4*)(xacc + recl * 32);
        const u16x8 b0 = __builtin_bit_cast(u16x8, src[0]);
        const u16x8 b1 = __builtin_bit_cast(u16x8, src[1]);
        const u16x8 b2 = __builtin_bit_cast(u16x8, src[2]);
        const u16x8 b3 = __builtin_bit_cast(u16x8, src[3]);
        u16x8 o0, o1, o2, o3;
#pragma unroll
        for (int j = 0; j < 8; ++j) {
            o0[j] = f2bf(accA[j]      + bf2f(b0[j]));
            o1[j] = f2bf(accA[8 + j]  + bf2f(b1[j]));
            o2[j] = f2bf(accB[j]      + bf2f(b2[j]));
            o3[j] = f2bf(accB[8 + j]  + bf2f(b3[j]));
        }
        const size_t base =
            ((((size_t)kq * 256 + qblk) * 2 + qhalf) * 64 + lane) * 32;
        uint4* gdst = (uint4*)(nump + base);
        gdst[0] = __builtin_bit_cast(uint4, o0);
        gdst[1] = __builtin_bit_cast(uint4, o1);
        gdst[2] = __builtin_bit_cast(uint4, o2);
        gdst[3] = __builtin_bit_cast(uint4, o3);
        if (half == 0)
            denp[(size_t)kq * NPOS + i0 + qhalf * 32 + m] =
                dw + xden[qhalf * 32 + m];
    }
}

// ---------------------------------------------------------------------------
// Finalize, record-major (coalesced reads). Block b = (qblk = b>>1, qh = b&1),
// thread t: lane = t>>2, u = t&3. den pre-reduced in LDS (4 partials).
// Element j of uint4 u: off = u*8+j, chigh = off>>4, r = off&15,
// c = chigh*32 + (lane&31), row = (r&3) + 8*(r>>2) + 4*(lane>>5).
// ---------------------------------------------------------------------------
__global__ __launch_bounds__(256) void finalize_kernel(
    const float* __restrict__ x,
    const unsigned short* __restrict__ nump,
    const float* __restrict__ denp,
    const float* __restrict__ gamma,
    float* __restrict__ out)
{
    const int b    = blockIdx.x;      // 0..511
    const int qblk = b >> 1;
    const int qh   = b & 1;
    const int t    = threadIdx.x;
    const int lane = t >> 2;
    const int u    = t & 3;
    const int n0   = qblk * 64 + qh * 32;

    __shared__ float dsum[32];
    if (t < 32) dsum[t] = 0.f;
    __syncthreads();
    if (t < 128)   // 4 kq x 32 rows
        atomicAdd(&dsum[t & 31], denp[(size_t)(t >> 5) * NPOS + n0 + (t & 31)]);
    __syncthreads();

    float ns[8];
#pragma unroll
    for (int j = 0; j < 8; ++j) ns[j] = 0.f;
#pragma unroll
    for (int kq = 0; kq < 4; ++kq) {
        const size_t base =
            ((((size_t)kq * 256 + qblk) * 2 + qh) * 64 + lane) * 32 + u * 8;
        const u16x8 h = __builtin_bit_cast(u16x8, *(const uint4*)(nump + base));
#pragma unroll
        for (int j = 0; j < 8; ++j) ns[j] += bf2f(h[j]);
    }

    const float g     = gamma[0];
    const int   clow  = lane & 31;
    const int   hf    = lane >> 5;
    const int   chigh = u >> 1;
    const int   c     = chigh * 32 + clow;
#pragma unroll
    for (int j = 0; j < 8; ++j) {
        const int off = u * 8 + j;
        const int r   = off & 15;
        const int row = (r & 3) + 8 * (r >> 2) + 4 * hf;
        const int n   = n0 + row;
        const size_t gi = (size_t)c * NPOS + n;
        out[gi] = fmaf(g, ns[j] * __builtin_amdgcn_rcpf(dsum[row]), x[gi]);
    }
}

// ---------------------------------------------------------------------------
extern "C" void kernel_launch(void* const* d_in, const int* in_sizes, int n_in,
                              void* d_out, int out_size, void* d_ws, size_t ws_size,
                              hipStream_t stream)
{
    (void)in_sizes; (void)n_in; (void)out_size; (void)ws_size;

    const float* x     = (const float*)d_in[0];
    const float* wq    = (const float*)d_in[1];
    const float* bq    = (const float*)d_in[2];
    const float* wk    = (const float*)d_in[3];
    const float* bk    = (const float*)d_in[4];
    const float* wv    = (const float*)d_in[5];
    const float* bv    = (const float*)d_in[6];
    const float* gamma = (const float*)d_in[7];
    float* out = (float*)d_out;

    char* ws = (char*)d_ws;
    unsigned short* qb16 = (unsigned short*)(ws);               // 256 KB
    unsigned short* kb16 = (unsigned short*)(ws + 262144);      // 256 KB
    unsigned char*  vb8  = (unsigned char*)(ws + 524288);       // 1 MB fp8
    unsigned short* nump = (unsigned short*)(ws + 1572864);     // 8 MB bf16
    float*          denp = (float*)(ws + 9961472);              // 256 KB

    proj_kernel<<<dim3(NPOS / 256, 10), 256, 0, stream>>>(
        x, wq, bq, wk, bk, wv, bv, qb16, kb16, vb8);
    attn_kernel<<<(NPOS / 64) * KSPLIT, 256, 0, stream>>>(
        (const uint4*)qb16, (const uint4*)kb16, (const uint2v*)vb8,
        nump, denp);
    finalize_kernel<<<512, 256, 0, stream>>>(x, nump, denp, gamma, out);
}

// Round 15
// 137.953 us; speedup vs baseline: 1.0511x; 1.0511x over previous
//
#include <hip/hip_runtime.h>

#define NPOS 16384   // D*H*W
#define KSPLIT 8
#define KEYS_PER_BLK (NPOS / KSPLIT)   // 2048
#define CHUNK 512
#define LOG2E 1.4426950408889634f

typedef short bf16x8 __attribute__((ext_vector_type(8)));
typedef unsigned short u16x8 __attribute__((ext_vector_type(8)));
typedef float floatx16 __attribute__((ext_vector_type(16)));
typedef float floatx2 __attribute__((ext_vector_type(2)));

static __device__ __forceinline__ unsigned short f2bf(float f) {
    return (unsigned short)(__builtin_bit_cast(unsigned int, f) >> 16);
}
static __device__ __forceinline__ float bf2f(unsigned short h) {
    return __builtin_bit_cast(float, (unsigned int)h << 16);
}

#if __has_builtin(__builtin_amdgcn_exp2f)
static __device__ __forceinline__ float exp2_fast(float x) {
    return __builtin_amdgcn_exp2f(x);
}
#else
static __device__ __forceinline__ float exp2_fast(float x) {
    float r;
    asm("v_exp_f32 %0, %1" : "=v"(r) : "v"(x));
    return r;
}
#endif

// pack hi16(a_even)|hi16(a_odd) -> one VGPR with 2 bf16 (even in low half)
static __device__ __forceinline__ unsigned int pk_bf16(float e_even, float e_odd) {
    return __builtin_amdgcn_perm(__builtin_bit_cast(unsigned int, e_odd),
                                 __builtin_bit_cast(unsigned int, e_even),
                                 0x07060302u);
}

// sigma: swap middle two 4-key nibbles per 16 keys (involution)
static __device__ __forceinline__ int sigma(int n) {
    const int w12 = n & 12;
    return (w12 == 4 || w12 == 8) ? (n ^ 12) : n;
}

// ---------------------------------------------------------------------------
// Projection. Grid (64, 10), block 256. Thread = position n x group g.
// g==0: q[0..7] (prescaled log2e) -> qb16 [n][8] bf16.
// g==1: k[0..7] -> kb16 [n][8] bf16 (natural key order).
// g>=2: v channels (g-2)*8..+7 -> vbg16 bf16, sigma-space group-major:
//   ushort index = (sigma(n)>>3)*512 + ch*8 + (sigma(n)&7)
//   ([key-group of 8][64 ch][8 keys] -> PV B-frag = one coalesced 16B load)
// ---------------------------------------------------------------------------
__global__ __launch_bounds__(256) void proj_kernel(
    const float* __restrict__ x,
    const float* __restrict__ wq, const float* __restrict__ bq,
    const float* __restrict__ wk, const float* __restrict__ bk,
    const float* __restrict__ wv, const float* __restrict__ bv,
    unsigned short* __restrict__ qb16, unsigned short* __restrict__ kb16,
    unsigned short* __restrict__ vbg16)
{
    const int t = threadIdx.x;
    const int n = blockIdx.x * 256 + t;
    const int g = blockIdx.y;

    const float* w;
    const float* b;
    if (g == 0)      { w = wq; b = bq; }
    else if (g == 1) { w = wk; b = bk; }
    else             { w = wv + (g - 2) * 8 * 64; b = bv + (g - 2) * 8; }

    float acc[8];
#pragma unroll
    for (int oo = 0; oo < 8; ++oo) acc[oo] = b[oo];
#pragma unroll 16
    for (int c = 0; c < 64; ++c) {
        const float xv = x[c * NPOS + n];
#pragma unroll
        for (int oo = 0; oo < 8; ++oo)
            acc[oo] = fmaf(w[oo * 64 + c], xv, acc[oo]);
    }

    if (g == 0) {
        u16x8 qp;
#pragma unroll
        for (int j = 0; j < 8; ++j) qp[j] = f2bf(acc[j] * LOG2E);
        ((uint4*)qb16)[n] = __builtin_bit_cast(uint4, qp);
    } else if (g == 1) {
        u16x8 kp;
#pragma unroll
        for (int j = 0; j < 8; ++j) kp[j] = f2bf(acc[j]);
        ((uint4*)kb16)[n] = __builtin_bit_cast(uint4, kp);
    } else {
        const int o0 = (g - 2) * 8;
        const int np = sigma(n);
        const size_t base = (size_t)(np >> 3) * 512 + (np & 7);
#pragma unroll
        for (int oo = 0; oo < 8; ++oo)
            vbg16[base + (size_t)(o0 + oo) * 8] = f2bf(acc[oo]);
    }
}

// ---------------------------------------------------------------------------
// Attention partials. Grid = 256 qblocks x 8 kq, 256 threads (4 waves).
// Wave (qhalf, khalf): 32 queries x 256-key half of each 512-key chunk.
// R10 structure (best measured: 57.7 us) + two derisked micro-fixes.
//
// Scores TRANSPOSED: T = K*Q^T via mfma_32x32x16_bf16, A[m=key][k=chan]
// from LDS (NO half1 zeroing: Q B-operand k>=8 rows are zero, so A's k>=8
// lanes multiply by 0 -- finite garbage is harmless), B[k=chan][n=query]
// (half1 zero). C/D: lane(l&31)=query, row r -> key (r&3)+8*(r>>2)+4*half.
// With V in sigma key order the PV A-frag f is exactly regs P[4f..4f+3].
// V direct from global (sigma-space group-major, L2-resident, coalesced).
// unroll 2 = two independent tile chains (proven best ILP point); den in 2
// rotating accumulators so the two chains don't serialize on one register.
// Epilogue: khalf merge via LDS; den stored per-kq (no atomics/memset).
// ---------------------------------------------------------------------------
__global__ __launch_bounds__(256, 4) void attn_kernel(
    const uint4* __restrict__ qb4,   // [n] 8 bf16 (prescaled log2e)
    const uint4* __restrict__ kb4,   // [n] 8 bf16, natural order
    const uint4* __restrict__ vbg4,  // [key/8][64 ch] uint4 bf16, sigma space
    unsigned short* __restrict__ nump,  // [8][256][2][64][32] bf16
    float* __restrict__ denp)           // [8][NPOS] fp32
{
    __shared__ __align__(16) char smem[8448];
    uint4* k_lds = (uint4*)smem;   // 512 keys (8 KB); epilogue aliases

    const int t     = threadIdx.x;
    const int wave  = t >> 6;
    const int lane  = t & 63;
    const int m     = lane & 31;
    const int half  = lane >> 5;
    const int qhalf = wave >> 1;
    const int khalf = wave & 1;

    const int qblk = blockIdx.x >> 3;
    const int kq   = blockIdx.x & 7;
    const int i0   = qblk * 64;
    const int jb   = kq * KEYS_PER_BLK;

    // B operand (queries): lane m = query qhalf*32+m, regs = chans, half1 zero
    uint4 qa4 = (half == 0) ? qb4[i0 + qhalf * 32 + m] : make_uint4(0, 0, 0, 0);
    const bf16x8 bqf = __builtin_bit_cast(bf16x8, qa4);

    floatx16 accA = {};            // channels 0..31
    floatx16 accB = {};            // channels 32..63
    floatx2  dacc[2];              // rotating den accumulators
    dacc[0] = (floatx2){0.f, 0.f};
    dacc[1] = (floatx2){0.f, 0.f};

#pragma unroll 1
    for (int c4 = 0; c4 < 4; ++c4) {
        const int j0 = jb + c4 * CHUNK;
        __syncthreads();
        k_lds[t]       = kb4[j0 + t];
        k_lds[256 + t] = kb4[j0 + 256 + t];
        __syncthreads();

        const int kwb = khalf * 256;   // wave's 256-key window in chunk
#pragma unroll 2
        for (int st = 0; st < 8; ++st) {
            const int kb_ = kwb + st * 32;   // tile base within chunk
            // A = K rows from LDS; half1 lanes read valid-but-unused data
            const bf16x8 ak = __builtin_bit_cast(bf16x8, k_lds[kb_ + m]);
            const floatx16 s = __builtin_amdgcn_mfma_f32_32x32x16_bf16(
                ak, bqf, (floatx16){}, 0, 0, 0);

            float e[16];
#pragma unroll
            for (int r = 0; r < 16; ++r) e[r] = exp2_fast(s[r]);
#pragma unroll
            for (int p = 0; p < 8; ++p)
                dacc[p & 1] += (floatx2){e[2 * p], e[2 * p + 1]};
            unsigned int P[8];
#pragma unroll
            for (int p = 0; p < 8; ++p) P[p] = pk_bf16(e[2 * p], e[2 * p + 1]);

            const int g8t = (j0 + kb_) >> 3;   // tile's 8-key group base
#pragma unroll
            for (int f = 0; f < 2; ++f) {
                uint4 afu;
                afu.x = P[4 * f + 0];
                afu.y = P[4 * f + 1];
                afu.z = P[4 * f + 2];
                afu.w = P[4 * f + 3];
                const bf16x8 af = __builtin_bit_cast(bf16x8, afu);

                const int g8 = g8t + f * 2 + half;
                const bf16x8 v0 = __builtin_bit_cast(
                    bf16x8, vbg4[(size_t)g8 * 64 + m]);
                const bf16x8 v1 = __builtin_bit_cast(
                    bf16x8, vbg4[(size_t)g8 * 64 + 32 + m]);
                accA = __builtin_amdgcn_mfma_f32_32x32x16_bf16(af, v0, accA,
                                                               0, 0, 0);
                accB = __builtin_amdgcn_mfma_f32_32x32x16_bf16(af, v1, accB,
                                                               0, 0, 0);
            }
        }
    }

    // per-query den for this wave (both halves end up holding it)
    const floatx2 dfold = dacc[0] + dacc[1];
    const float dl = dfold[0] + dfold[1];
    const float dw = dl + __shfl_xor(dl, 32);

    // khalf-pair merge via LDS (aliases k_lds; safe after barrier)
    __syncthreads();
    float*          xden = (float*)smem;                    // 64 f32
    unsigned short* xacc = (unsigned short*)(smem + 256);   // [2][64][32]
    const int recl = qhalf * 64 + lane;
    if (khalf == 1) {
        if (half == 0) xden[qhalf * 32 + m] = dw;
        u16x8 a0, a1, a2, a3;
#pragma unroll
        for (int j = 0; j < 8; ++j) {
            a0[j] = f2bf(accA[j]);
            a1[j] = f2bf(accA[8 + j]);
            a2[j] = f2bf(accB[j]);
            a3[j] = f2bf(accB[8 + j]);
        }
        uint4* dst = (uint4*)(xacc + recl * 32);
        dst[0] = __builtin_bit_cast(uint4, a0);
        dst[1] = __builtin_bit_cast(uint4, a1);
        dst[2] = __builtin_bit_cast(uint4, a2);
        dst[3] = __builtin_bit_cast(uint4, a3);
    }
    __syncthreads();
    if (khalf == 0) {
        const uint4* src = (const uint4*)(xacc + recl * 32);
        const u16x8 b0 = __builtin_bit_cast(u16x8, src[0]);
        const u16x8 b1 = __builtin_bit_cast(u16x8, src[1]);
        const u16x8 b2 = __builtin_bit_cast(u16x8, src[2]);
        const u16x8 b3 = __builtin_bit_cast(u16x8, src[3]);
        u16x8 o0, o1, o2, o3;
#pragma unroll
        for (int j = 0; j < 8; ++j) {
            o0[j] = f2bf(accA[j]      + bf2f(b0[j]));
            o1[j] = f2bf(accA[8 + j]  + bf2f(b1[j]));
            o2[j] = f2bf(accB[j]      + bf2f(b2[j]));
            o3[j] = f2bf(accB[8 + j]  + bf2f(b3[j]));
        }
        const size_t base =
            ((((size_t)kq * 256 + qblk) * 2 + qhalf) * 64 + lane) * 32;
        uint4* gdst = (uint4*)(nump + base);
        gdst[0] = __builtin_bit_cast(uint4, o0);
        gdst[1] = __builtin_bit_cast(uint4, o1);
        gdst[2] = __builtin_bit_cast(uint4, o2);
        gdst[3] = __builtin_bit_cast(uint4, o3);
        if (half == 0)
            denp[(size_t)kq * NPOS + i0 + qhalf * 32 + m] =
                dw + xden[qhalf * 32 + m];
    }
}

// ---------------------------------------------------------------------------
// Finalize: coalesced reads AND writes via LDS transpose.
// Block b = (qblk = b>>1, qh = b&1). Phase 1: den 8x32 -> dsum (LDS atomics).
// Phase 2: thread (lane = t>>2, u = t&3) reads one uint4 per kq (coalesced),
// sums, scatters into ot[row][c] in LDS: off = u*8+j, r = off&15,
// row = (r&3)+8*(r>>2)+4*(lane>>5), c = (off>>4)*32 + (lane&31).
// Phase 3: thread t = (c = t>>2, nq = t&3) writes out[c][n0+nq*8 .. +7]
// contiguous (16 cache lines per wave instead of 64 in the old scatter).
// ---------------------------------------------------------------------------
__global__ __launch_bounds__(256) void finalize_kernel(
    const float* __restrict__ x,
    const unsigned short* __restrict__ nump,
    const float* __restrict__ denp,
    const float* __restrict__ gamma,
    float* __restrict__ out)
{
    const int b    = blockIdx.x;      // 0..511
    const int qblk = b >> 1;
    const int qh   = b & 1;
    const int t    = threadIdx.x;
    const int lane = t >> 2;
    const int u    = t & 3;
    const int n0   = qblk * 64 + qh * 32;

    __shared__ float dsum[32];
    __shared__ float ot[32 * 66];   // [row][c], padded
    if (t < 32) dsum[t] = 0.f;
    __syncthreads();
    atomicAdd(&dsum[t & 31], denp[(size_t)(t >> 5) * NPOS + n0 + (t & 31)]);

    float ns[8];
#pragma unroll
    for (int j = 0; j < 8; ++j) ns[j] = 0.f;
#pragma unroll
    for (int kq = 0; kq < 8; ++kq) {
        const size_t base =
            ((((size_t)kq * 256 + qblk) * 2 + qh) * 64 + lane) * 32 + u * 8;
        const u16x8 h = __builtin_bit_cast(u16x8, *(const uint4*)(nump + base));
#pragma unroll
        for (int j = 0; j < 8; ++j) ns[j] += bf2f(h[j]);
    }

    const int clow = lane & 31;
    const int hf   = lane >> 5;
#pragma unroll
    for (int j = 0; j < 8; ++j) {
        const int off = u * 8 + j;
        const int r   = off & 15;
        const int row = (r & 3) + 8 * (r >> 2) + 4 * hf;
        const int c   = (off >> 4) * 32 + clow;
        ot[row * 66 + c] = ns[j];
    }
    __syncthreads();

    const float g  = gamma[0];
    const int   c2 = t >> 2;         // channel 0..63
    const int   nq = t & 3;          // n-octet 0..3
    const int   nb = nq * 8;
#pragma unroll
    for (int j = 0; j < 8; ++j) {
        const int row = nb + j;
        const size_t gi = (size_t)c2 * NPOS + n0 + row;
        out[gi] = fmaf(g, ot[row * 66 + c2] *
                              __builtin_amdgcn_rcpf(dsum[row]), x[gi]);
    }
}

// ---------------------------------------------------------------------------
extern "C" void kernel_launch(void* const* d_in, const int* in_sizes, int n_in,
                              void* d_out, int out_size, void* d_ws, size_t ws_size,
                              hipStream_t stream)
{
    (void)in_sizes; (void)n_in; (void)out_size; (void)ws_size;

    const float* x     = (const float*)d_in[0];
    const float* wq    = (const float*)d_in[1];
    const float* bq    = (const float*)d_in[2];
    const float* wk    = (const float*)d_in[3];
    const float* bk    = (const float*)d_in[4];
    const float* wv    = (const float*)d_in[5];
    const float* bv    = (const float*)d_in[6];
    const float* gamma = (const float*)d_in[7];
    float* out = (float*)d_out;

    char* ws = (char*)d_ws;
    unsigned short* qb16  = (unsigned short*)(ws);              // 256 KB
    unsigned short* kb16  = (unsigned short*)(ws + 262144);     // 256 KB
    unsigned short* vbg16 = (unsigned short*)(ws + 524288);     // 2 MB
    unsigned short* nump  = (unsigned short*)(ws + 2621440);    // 16 MB bf16
    float*          denp  = (float*)(ws + 19398656);            // 512 KB

    proj_kernel<<<dim3(NPOS / 256, 10), 256, 0, stream>>>(
        x, wq, bq, wk, bk, wv, bv, qb16, kb16, vbg16);
    attn_kernel<<<(NPOS / 64) * KSPLIT, 256, 0, stream>>>(
        (const uint4*)qb16, (const uint4*)kb16, (const uint4*)vbg16,
        nump, denp);
    finalize_kernel<<<512, 256, 0, stream>>>(x, nump, denp, gamma, out);
}

// Round 16
// 132.899 us; speedup vs baseline: 1.0911x; 1.0380x over previous
//
#include <hip/hip_runtime.h>

#define NPOS 16384   // D*H*W
#define KSPLIT 8
#define KEYS_PER_BLK (NPOS / KSPLIT)   // 2048
#define CHUNK 512
#define LOG2E 1.4426950408889634f

typedef short bf16x8 __attribute__((ext_vector_type(8)));
typedef unsigned short u16x8 __attribute__((ext_vector_type(8)));
typedef float floatx16 __attribute__((ext_vector_type(16)));
typedef float floatx2 __attribute__((ext_vector_type(2)));

static __device__ __forceinline__ unsigned short f2bf(float f) {
    return (unsigned short)(__builtin_bit_cast(unsigned int, f) >> 16);
}
static __device__ __forceinline__ float bf2f(unsigned short h) {
    return __builtin_bit_cast(float, (unsigned int)h << 16);
}

#if __has_builtin(__builtin_amdgcn_exp2f)
static __device__ __forceinline__ float exp2_fast(float x) {
    return __builtin_amdgcn_exp2f(x);
}
#else
static __device__ __forceinline__ float exp2_fast(float x) {
    float r;
    asm("v_exp_f32 %0, %1" : "=v"(r) : "v"(x));
    return r;
}
#endif

// pack hi16(a_even)|hi16(a_odd) -> one VGPR with 2 bf16 (even in low half)
static __device__ __forceinline__ unsigned int pk_bf16(float e_even, float e_odd) {
    return __builtin_amdgcn_perm(__builtin_bit_cast(unsigned int, e_odd),
                                 __builtin_bit_cast(unsigned int, e_even),
                                 0x07060302u);
}

// sigma: swap middle two 4-key nibbles per 16 keys (involution)
static __device__ __forceinline__ int sigma(int n) {
    const int w12 = n & 12;
    return (w12 == 4 || w12 == 8) ? (n ^ 12) : n;
}

// ---------------------------------------------------------------------------
// Projection (unchanged from R15). Grid (64, 10), block 256.
// g==0: q (prescaled log2e) -> qb16 [n][8] bf16. g==1: k -> kb16.
// g>=2: v channels (g-2)*8..+7 -> vbg16 bf16, sigma-space group-major:
//   ushort index = (sigma(n)>>3)*512 + ch*8 + (sigma(n)&7)
// ---------------------------------------------------------------------------
__global__ __launch_bounds__(256) void proj_kernel(
    const float* __restrict__ x,
    const float* __restrict__ wq, const float* __restrict__ bq,
    const float* __restrict__ wk, const float* __restrict__ bk,
    const float* __restrict__ wv, const float* __restrict__ bv,
    unsigned short* __restrict__ qb16, unsigned short* __restrict__ kb16,
    unsigned short* __restrict__ vbg16)
{
    const int t = threadIdx.x;
    const int n = blockIdx.x * 256 + t;
    const int g = blockIdx.y;

    const float* w;
    const float* b;
    if (g == 0)      { w = wq; b = bq; }
    else if (g == 1) { w = wk; b = bk; }
    else             { w = wv + (g - 2) * 8 * 64; b = bv + (g - 2) * 8; }

    float acc[8];
#pragma unroll
    for (int oo = 0; oo < 8; ++oo) acc[oo] = b[oo];
#pragma unroll 16
    for (int c = 0; c < 64; ++c) {
        const float xv = x[c * NPOS + n];
#pragma unroll
        for (int oo = 0; oo < 8; ++oo)
            acc[oo] = fmaf(w[oo * 64 + c], xv, acc[oo]);
    }

    if (g == 0) {
        u16x8 qp;
#pragma unroll
        for (int j = 0; j < 8; ++j) qp[j] = f2bf(acc[j] * LOG2E);
        ((uint4*)qb16)[n] = __builtin_bit_cast(uint4, qp);
    } else if (g == 1) {
        u16x8 kp;
#pragma unroll
        for (int j = 0; j < 8; ++j) kp[j] = f2bf(acc[j]);
        ((uint4*)kb16)[n] = __builtin_bit_cast(uint4, kp);
    } else {
        const int o0 = (g - 2) * 8;
        const int np = sigma(n);
        const size_t base = (size_t)(np >> 3) * 512 + (np & 7);
#pragma unroll
        for (int oo = 0; oo < 8; ++oo)
            vbg16[base + (size_t)(o0 + oo) * 8] = f2bf(acc[oo]);
    }
}

// ---------------------------------------------------------------------------
// Attention partials, 2-qtile-per-wave pairing. Grid = 128 qblocks(128q) x
// 8 kq = 1024 blocks (= exact 4-blocks/CU co-residency, no tail), 256 thr.
// Wave (qpair, khalf): TWO 32-query tiles (qpair*64 .. +63) x 256-key half
// of each 512-key chunk. Both tiles share the same K fragment and V
// fragments (halves K-LDS reads + V-L2 loads per score) and give two
// naturally independent score->exp->pack->PV chains (ILP without unroll
// register pressure; unroll back to 1).
//
// Per tile (unchanged algebra): T = K*Q^T via mfma_32x32x16_bf16,
// A[m=key][k=chan] from LDS (no half1 zeroing -- Q's k>=8 rows are zero),
// B[k=chan][n=query] (half1 zero). C/D: lane(l&31)=query, row r -> key
// (r&3)+8*(r>>2)+4*half. With V in sigma key order the PV A-frag f is
// exactly regs P[4f..4f+3].
// Epilogue: khalf merge via LDS (2 records/wave); den per-kq stores.
// ---------------------------------------------------------------------------
__global__ __launch_bounds__(256, 4) void attn_kernel(
    const uint4* __restrict__ qb4,   // [n] 8 bf16 (prescaled log2e)
    const uint4* __restrict__ kb4,   // [n] 8 bf16, natural order
    const uint4* __restrict__ vbg4,  // [key/8][64 ch] uint4 bf16, sigma space
    unsigned short* __restrict__ nump,  // [8][512][64][32] bf16
    float* __restrict__ denp)           // [8][NPOS] fp32
{
    __shared__ __align__(16) char smem[16896];
    uint4* k_lds = (uint4*)smem;   // 512 keys (8 KB); epilogue aliases

    const int t     = threadIdx.x;
    const int wave  = t >> 6;
    const int lane  = t & 63;
    const int m     = lane & 31;
    const int half  = lane >> 5;
    const int qpair = wave >> 1;
    const int khalf = wave & 1;

    const int qblk = blockIdx.x >> 3;
    const int kq   = blockIdx.x & 7;
    const int i0   = qblk * 128;
    const int jb   = kq * KEYS_PER_BLK;
    const int qt0  = (i0 >> 5) + qpair * 2;   // absolute 32q-tile ids qt0,qt0+1

    const uint4 zero4 = make_uint4(0, 0, 0, 0);
    const uint4 qLo4 = (half == 0) ? qb4[i0 + qpair * 64 + m]      : zero4;
    const uint4 qHi4 = (half == 0) ? qb4[i0 + qpair * 64 + 32 + m] : zero4;
    const bf16x8 bqLo = __builtin_bit_cast(bf16x8, qLo4);
    const bf16x8 bqHi = __builtin_bit_cast(bf16x8, qHi4);

    floatx16 accLoA = {}, accLoB = {};   // tile Lo, ch 0..31 / 32..63
    floatx16 accHiA = {}, accHiB = {};   // tile Hi
    floatx2  dLo = {0.f, 0.f}, dHi = {0.f, 0.f};

#pragma unroll 1
    for (int c4 = 0; c4 < 4; ++c4) {
        const int j0 = jb + c4 * CHUNK;
        __syncthreads();
        k_lds[t]       = kb4[j0 + t];
        k_lds[256 + t] = kb4[j0 + 256 + t];
        __syncthreads();

        const int kwb = khalf * 256;   // wave's 256-key window in chunk
#pragma unroll 1
        for (int st = 0; st < 8; ++st) {
            const int kb_ = kwb + st * 32;
            const bf16x8 ak = __builtin_bit_cast(bf16x8, k_lds[kb_ + m]);
            const floatx16 sLo = __builtin_amdgcn_mfma_f32_32x32x16_bf16(
                ak, bqLo, (floatx16){}, 0, 0, 0);
            const floatx16 sHi = __builtin_amdgcn_mfma_f32_32x32x16_bf16(
                ak, bqHi, (floatx16){}, 0, 0, 0);

            // V fragments: shared by both tiles
            const int g8t = (j0 + kb_) >> 3;
            bf16x8 vf0[2], vf1[2];
#pragma unroll
            for (int f = 0; f < 2; ++f) {
                const int g8 = g8t + f * 2 + half;
                vf0[f] = __builtin_bit_cast(bf16x8, vbg4[(size_t)g8 * 64 + m]);
                vf1[f] = __builtin_bit_cast(bf16x8,
                                            vbg4[(size_t)g8 * 64 + 32 + m]);
            }

            // ---- tile Lo ----
            {
                float e[16];
#pragma unroll
                for (int r = 0; r < 16; ++r) e[r] = exp2_fast(sLo[r]);
#pragma unroll
                for (int p = 0; p < 8; ++p)
                    dLo += (floatx2){e[2 * p], e[2 * p + 1]};
                unsigned int P[8];
#pragma unroll
                for (int p = 0; p < 8; ++p)
                    P[p] = pk_bf16(e[2 * p], e[2 * p + 1]);
#pragma unroll
                for (int f = 0; f < 2; ++f) {
                    uint4 afu;
                    afu.x = P[4 * f + 0];
                    afu.y = P[4 * f + 1];
                    afu.z = P[4 * f + 2];
                    afu.w = P[4 * f + 3];
                    const bf16x8 af = __builtin_bit_cast(bf16x8, afu);
                    accLoA = __builtin_amdgcn_mfma_f32_32x32x16_bf16(
                        af, vf0[f], accLoA, 0, 0, 0);
                    accLoB = __builtin_amdgcn_mfma_f32_32x32x16_bf16(
                        af, vf1[f], accLoB, 0, 0, 0);
                }
            }
            // ---- tile Hi ----
            {
                float e[16];
#pragma unroll
                for (int r = 0; r < 16; ++r) e[r] = exp2_fast(sHi[r]);
#pragma unroll
                for (int p = 0; p < 8; ++p)
                    dHi += (floatx2){e[2 * p], e[2 * p + 1]};
                unsigned int P[8];
#pragma unroll
                for (int p = 0; p < 8; ++p)
                    P[p] = pk_bf16(e[2 * p], e[2 * p + 1]);
#pragma unroll
                for (int f = 0; f < 2; ++f) {
                    uint4 afu;
                    afu.x = P[4 * f + 0];
                    afu.y = P[4 * f + 1];
                    afu.z = P[4 * f + 2];
                    afu.w = P[4 * f + 3];
                    const bf16x8 af = __builtin_bit_cast(bf16x8, afu);
                    accHiA = __builtin_amdgcn_mfma_f32_32x32x16_bf16(
                        af, vf0[f], accHiA, 0, 0, 0);
                    accHiB = __builtin_amdgcn_mfma_f32_32x32x16_bf16(
                        af, vf1[f], accHiB, 0, 0, 0);
                }
            }
        }
    }

    // per-query den (each tile): fold pair, combine khalves
    const float dlLo = dLo[0] + dLo[1];
    const float dwLo = dlLo + __shfl_xor(dlLo, 32);
    const float dlHi = dHi[0] + dHi[1];
    const float dwHi = dlHi + __shfl_xor(dlHi, 32);

    // khalf-pair merge via LDS (aliases k_lds; safe after barrier)
    __syncthreads();
    float*          xden = (float*)smem;                    // 128 f32
    unsigned short* xacc = (unsigned short*)(smem + 512);   // [4][64][32]
    if (khalf == 1) {
        if (half == 0) {
            xden[(qpair * 2 + 0) * 32 + m] = dwLo;
            xden[(qpair * 2 + 1) * 32 + m] = dwHi;
        }
#pragma unroll
        for (int tile = 0; tile < 2; ++tile) {
            const floatx16* aA = tile ? &accHiA : &accLoA;
            const floatx16* aB = tile ? &accHiB : &accLoB;
            u16x8 a0, a1, a2, a3;
#pragma unroll
            for (int j = 0; j < 8; ++j) {
                a0[j] = f2bf((*aA)[j]);
                a1[j] = f2bf((*aA)[8 + j]);
                a2[j] = f2bf((*aB)[j]);
                a3[j] = f2bf((*aB)[8 + j]);
            }
            uint4* dst = (uint4*)(xacc + ((qpair * 2 + tile) * 64 + lane) * 32);
            dst[0] = __builtin_bit_cast(uint4, a0);
            dst[1] = __builtin_bit_cast(uint4, a1);
            dst[2] = __builtin_bit_cast(uint4, a2);
            dst[3] = __builtin_bit_cast(uint4, a3);
        }
    }
    __syncthreads();
    if (khalf == 0) {
#pragma unroll
        for (int tile = 0; tile < 2; ++tile) {
            const floatx16* aA = tile ? &accHiA : &accLoA;
            const floatx16* aB = tile ? &accHiB : &accLoB;
            const uint4* src =
                (const uint4*)(xacc + ((qpair * 2 + tile) * 64 + lane) * 32);
            const u16x8 b0 = __builtin_bit_cast(u16x8, src[0]);
            const u16x8 b1 = __builtin_bit_cast(u16x8, src[1]);
            const u16x8 b2 = __builtin_bit_cast(u16x8, src[2]);
            const u16x8 b3 = __builtin_bit_cast(u16x8, src[3]);
            u16x8 o0, o1, o2, o3;
#pragma unroll
            for (int j = 0; j < 8; ++j) {
                o0[j] = f2bf((*aA)[j]      + bf2f(b0[j]));
                o1[j] = f2bf((*aA)[8 + j]  + bf2f(b1[j]));
                o2[j] = f2bf((*aB)[j]      + bf2f(b2[j]));
                o3[j] = f2bf((*aB)[8 + j]  + bf2f(b3[j]));
            }
            const size_t base =
                (((size_t)kq * 512 + qt0 + tile) * 64 + lane) * 32;
            uint4* gdst = (uint4*)(nump + base);
            gdst[0] = __builtin_bit_cast(uint4, o0);
            gdst[1] = __builtin_bit_cast(uint4, o1);
            gdst[2] = __builtin_bit_cast(uint4, o2);
            gdst[3] = __builtin_bit_cast(uint4, o3);
        }
        if (half == 0) {
            denp[(size_t)kq * NPOS + (qt0 + 0) * 32 + m] =
                dwLo + xden[(qpair * 2 + 0) * 32 + m];
            denp[(size_t)kq * NPOS + (qt0 + 1) * 32 + m] =
                dwHi + xden[(qpair * 2 + 1) * 32 + m];
        }
    }
}

// ---------------------------------------------------------------------------
// Finalize (R15 structure, re-indexed by absolute 32q tile b = blockIdx.x).
// Phase 1: den 8x32 -> dsum (LDS atomics). Phase 2: coalesced record reads,
// LDS transpose ot[row][c]. Phase 3: coalesced writes out[c][n0..n0+31].
// ---------------------------------------------------------------------------
__global__ __launch_bounds__(256) void finalize_kernel(
    const float* __restrict__ x,
    const unsigned short* __restrict__ nump,
    const float* __restrict__ denp,
    const float* __restrict__ gamma,
    float* __restrict__ out)
{
    const int b    = blockIdx.x;      // 0..511 = 32q tile
    const int t    = threadIdx.x;
    const int lane = t >> 2;
    const int u    = t & 3;
    const int n0   = b * 32;

    __shared__ float dsum[32];
    __shared__ float ot[32 * 66];   // [row][c], padded
    if (t < 32) dsum[t] = 0.f;
    __syncthreads();
    atomicAdd(&dsum[t & 31], denp[(size_t)(t >> 5) * NPOS + n0 + (t & 31)]);

    float ns[8];
#pragma unroll
    for (int j = 0; j < 8; ++j) ns[j] = 0.f;
#pragma unroll
    for (int kq = 0; kq < 8; ++kq) {
        const size_t base =
            (((size_t)kq * 512 + b) * 64 + lane) * 32 + u * 8;
        const u16x8 h = __builtin_bit_cast(u16x8, *(const uint4*)(nump + base));
#pragma unroll
        for (int j = 0; j < 8; ++j) ns[j] += bf2f(h[j]);
    }

    const int clow = lane & 31;
    const int hf   = lane >> 5;
#pragma unroll
    for (int j = 0; j < 8; ++j) {
        const int off = u * 8 + j;
        const int r   = off & 15;
        const int row = (r & 3) + 8 * (r >> 2) + 4 * hf;
        const int c   = (off >> 4) * 32 + clow;
        ot[row * 66 + c] = ns[j];
    }
    __syncthreads();

    const float g  = gamma[0];
    const int   c2 = t >> 2;         // channel 0..63
    const int   nq = t & 3;          // n-octet 0..3
#pragma unroll
    for (int j = 0; j < 8; ++j) {
        const int row = nq * 8 + j;
        const size_t gi = (size_t)c2 * NPOS + n0 + row;
        out[gi] = fmaf(g, ot[row * 66 + c2] *
                              __builtin_amdgcn_rcpf(dsum[row]), x[gi]);
    }
}

// ---------------------------------------------------------------------------
extern "C" void kernel_launch(void* const* d_in, const int* in_sizes, int n_in,
                              void* d_out, int out_size, void* d_ws, size_t ws_size,
                              hipStream_t stream)
{
    (void)in_sizes; (void)n_in; (void)out_size; (void)ws_size;

    const float* x     = (const float*)d_in[0];
    const float* wq    = (const float*)d_in[1];
    const float* bq    = (const float*)d_in[2];
    const float* wk    = (const float*)d_in[3];
    const float* bk    = (const float*)d_in[4];
    const float* wv    = (const float*)d_in[5];
    const float* bv    = (const float*)d_in[6];
    const float* gamma = (const float*)d_in[7];
    float* out = (float*)d_out;

    char* ws = (char*)d_ws;
    unsigned short* qb16  = (unsigned short*)(ws);              // 256 KB
    unsigned short* kb16  = (unsigned short*)(ws + 262144);     // 256 KB
    unsigned short* vbg16 = (unsigned short*)(ws + 524288);     // 2 MB
    unsigned short* nump  = (unsigned short*)(ws + 2621440);    // 16 MB bf16
    float*          denp  = (float*)(ws + 19398656);            // 512 KB

    proj_kernel<<<dim3(NPOS / 256, 10), 256, 0, stream>>>(
        x, wq, bq, wk, bk, wv, bv, qb16, kb16, vbg16);
    attn_kernel<<<(NPOS / 128) * KSPLIT, 256, 0, stream>>>(
        (const uint4*)qb16, (const uint4*)kb16, (const uint4*)vbg16,
        nump, denp);
    finalize_kernel<<<512, 256, 0, stream>>>(x, nump, denp, gamma, out);
}